// Round 8
// baseline (216.825 us; speedup 1.0000x reference)
//
#include <hip/hip_runtime.h>
#include <hip/hip_bf16.h>

#define BF16 __hip_bfloat16

typedef __bf16 bf16x8 __attribute__((ext_vector_type(8)));
typedef float floatx4 __attribute__((ext_vector_type(4)));
typedef int intx4 __attribute__((ext_vector_type(4)));

// ---------------- fused transpose + fp32->bf16 convert (3 matrices, 1 launch) ----
__global__ __launch_bounds__(256) void transpose_all(const float* __restrict__ features,
                                                     const float* __restrict__ fc1_w,
                                                     const float* __restrict__ fc2_w,
                                                     BF16* __restrict__ featT,
                                                     BF16* __restrict__ w1t,
                                                     BF16* __restrict__ w2t) {
    __shared__ float tile[32][33];
    int bid = blockIdx.x;
    const float* ip;
    BF16* op;
    int R, C, cx, cy;
    if (bid < 6800) {
        int z = bid / 3400, r = bid - z * 3400;
        cx = r % 425; cy = r / 425;
        R = 256; C = 13600;
        ip = features + (size_t)z * 256 * 13600;
        op = featT + (size_t)z * 256 * 13600;
    } else if (bid < 19344) {
        int r = bid - 6800;
        cx = r & 31; cy = r >> 5;
        R = 12544; C = 1024;
        ip = fc1_w; op = w1t;
    } else {
        int r = bid - 19344;
        cx = r & 31; cy = r >> 5;
        R = 1024; C = 1024;
        ip = fc2_w; op = w2t;
    }
    int tx = threadIdx.x & 31, ty = threadIdx.x >> 5;
    int r0 = cy << 5, c0 = cx << 5;
#pragma unroll
    for (int i = 0; i < 4; ++i)
        tile[ty + i * 8][tx] = ip[(size_t)(r0 + ty + i * 8) * C + c0 + tx];
    __syncthreads();
#pragma unroll
    for (int i = 0; i < 4; ++i)
        op[(size_t)(c0 + ty + i * 8) * R + r0 + tx] = __float2bfloat16(tile[tx][ty + i * 8]);
}

// ---------------- ROI align (phase-split, 16B vector taps) ----------------
__global__ __launch_bounds__(256) void roi_align_k(const BF16* __restrict__ featT,
                                                   const float* __restrict__ boxes,
                                                   const int* __restrict__ roi_batch,
                                                   BF16* __restrict__ feats) {
    __shared__ __align__(16) int   s_off[196][4];
    __shared__ __align__(16) float s_w[196][4];
    __shared__ BF16 lbuf[12544];
    int roi = blockIdx.x;
    int t = threadIdx.x;
    BF16* orow = feats + (size_t)roi * 12544;
    if (roi >= 1000) {
        uint4* o4 = (uint4*)orow;
        uint4 z = {0u, 0u, 0u, 0u};
        for (int i = t; i < 1568; i += 256) o4[i] = z;
        return;
    }
    int b = roi_batch[roi];

    if (t < 196) {
        float x1 = boxes[roi * 4 + 0] * 0.125f;
        float y1 = boxes[roi * 4 + 1] * 0.125f;
        float x2 = boxes[roi * 4 + 2] * 0.125f;
        float y2 = boxes[roi * 4 + 3] * 0.125f;
        float bw = fmaxf(x2 - x1, 1.0f) * (1.0f / 7.0f);
        float bh = fmaxf(y2 - y1, 1.0f) * (1.0f / 7.0f);
        int cell = t >> 2, s = t & 3;
        int oy = cell / 7, ox = cell - oy * 7;
        int sy = s >> 1, sx = s & 1;
        float yc = y1 + ((float)oy + ((float)sy + 0.5f) * 0.5f) * bh;
        float xc = x1 + ((float)ox + ((float)sx + 0.5f) * 0.5f) * bw;
        yc = fminf(fmaxf(yc, 0.0f), 99.0f);
        xc = fminf(fmaxf(xc, 0.0f), 135.0f);
        float y0f = floorf(yc), x0f = floorf(xc);
        int y0 = (int)y0f, x0 = (int)x0f;
        int y1i = min(y0 + 1, 99), x1i = min(x0 + 1, 135);
        float ly = yc - y0f, lx = xc - x0f;
        s_w[t][0] = (1.0f - ly) * (1.0f - lx) * 0.25f;
        s_w[t][1] = (1.0f - ly) * lx * 0.25f;
        s_w[t][2] = ly * (1.0f - lx) * 0.25f;
        s_w[t][3] = ly * lx * 0.25f;
        s_off[t][0] = (y0 * 136 + x0) * 256;
        s_off[t][1] = (y0 * 136 + x1i) * 256;
        s_off[t][2] = (y1i * 136 + x0) * 256;
        s_off[t][3] = (y1i * 136 + x1i) * 256;
    }
    __syncthreads();

    int cb = t & 31, g = t >> 5;
    const BF16* fb = featT + (size_t)b * (100 * 136 * 256) + cb * 8;
    int chbase = cb * 8;
    for (int cell = g; cell < 49; cell += 8) {
        float a[8];
#pragma unroll
        for (int j = 0; j < 8; ++j) a[j] = 0.0f;
#pragma unroll
        for (int s = 0; s < 4; ++s) {
            int p = cell * 4 + s;
#pragma unroll
            for (int tap = 0; tap < 4; ++tap) {
                float w = s_w[p][tap];
                bf16x8 v = *(const bf16x8*)(fb + s_off[p][tap]);
#pragma unroll
                for (int j = 0; j < 8; ++j) a[j] += w * (float)v[j];
            }
        }
#pragma unroll
        for (int j = 0; j < 8; ++j)
            lbuf[(chbase + j) * 49 + cell] = __float2bfloat16(a[j]);
    }
    __syncthreads();
    uint4* o4 = (uint4*)orow;
    const uint4* l4 = (const uint4*)lbuf;
    for (int i = t; i < 1568; i += 256) o4[i] = l4[i];
}

// ---- split-K bf16 MFMA GEMM, 128x128 tile, BK=64, register-prefetch pipeline ----
// 1D grid, XCD-locality swizzle: tn = lin&7 so (heuristic: XCD = blockIdx%8)
// every block on XCD x reads the SAME B column-stripe -> B stays L2-resident
// (459 KB x S slices < 4 MB). tm/s enumerate within the XCD.
__global__ __launch_bounds__(256) void gemm_splitk(const BF16* __restrict__ A,
                                                   const BF16* __restrict__ Bt,
                                                   float* __restrict__ P,
                                                   int K, int chunk) {
    __shared__ char lds[2][2][16384];
    int w = threadIdx.x >> 6, l = threadIdx.x & 63;
    int wm = w & 1, wn = w >> 1;
    int lin = blockIdx.x;
    int tn = lin & 7;
    int tm = (lin >> 3) & 7;
    int s  = lin >> 6;
    int k0 = s * chunk;

    floatx4 acc[4][4];
#pragma unroll
    for (int i = 0; i < 4; ++i)
#pragma unroll
        for (int j = 0; j < 4; ++j) acc[i][j] = (floatx4){0.f, 0.f, 0.f, 0.f};

    const size_t strideA = (size_t)K * 2;
    int r8 = l >> 3;
    int g8 = (l & 7) ^ r8;
    const char* gA = (const char*)A + (size_t)(tm * 128 + w * 32 + r8) * strideA
                     + (size_t)k0 * 2 + (size_t)g8 * 16;
    const char* gB = (const char*)Bt + (size_t)(tn * 128 + w * 32 + r8) * strideA
                     + (size_t)k0 * 2 + (size_t)g8 * 16;
    int lw = w * 4096 + l * 16;

    int c = l & 15, q = l >> 4;
    int xa0 = ((0 * 4 + q) ^ (c & 7)) * 16;
    int xa1 = ((1 * 4 + q) ^ (c & 7)) * 16;
    int abase = (wm * 64 + c) * 128;
    int bbase = (wn * 64 + c) * 128;

    int nIter = chunk >> 6;

    intx4 pa[4], pb[4];
#pragma unroll
    for (int i = 0; i < 4; ++i) {
        pa[i] = *(const intx4*)(gA + (size_t)(i * 8) * strideA);
        pb[i] = *(const intx4*)(gB + (size_t)(i * 8) * strideA);
    }
#pragma unroll
    for (int i = 0; i < 4; ++i) {
        *(intx4*)(&lds[0][0][lw + i * 1024]) = pa[i];
        *(intx4*)(&lds[0][1][lw + i * 1024]) = pb[i];
    }
    __syncthreads();

    for (int kb = 0; kb < nIter; ++kb) {
        int cur = kb & 1;
        bool more = (kb + 1 < nIter);
        if (more) {
            size_t ko = (size_t)(kb + 1) * 128;
#pragma unroll
            for (int i = 0; i < 4; ++i) {
                pa[i] = *(const intx4*)(gA + (size_t)(i * 8) * strideA + ko);
                pb[i] = *(const intx4*)(gB + (size_t)(i * 8) * strideA + ko);
            }
        }
        const char* bufA = lds[cur][0];
        const char* bufB = lds[cur][1];
#pragma unroll
        for (int kk = 0; kk < 2; ++kk) {
            int xo = kk ? xa1 : xa0;
            bf16x8 af[4], bfr[4];
#pragma unroll
            for (int mi = 0; mi < 4; ++mi) af[mi] = *(const bf16x8*)(bufA + abase + mi * 2048 + xo);
#pragma unroll
            for (int ni = 0; ni < 4; ++ni) bfr[ni] = *(const bf16x8*)(bufB + bbase + ni * 2048 + xo);
#pragma unroll
            for (int mi = 0; mi < 4; ++mi)
#pragma unroll
                for (int ni = 0; ni < 4; ++ni)
                    acc[mi][ni] = __builtin_amdgcn_mfma_f32_16x16x32_bf16(af[mi], bfr[ni], acc[mi][ni], 0, 0, 0);
        }
        if (more) {
            char* nA = &lds[cur ^ 1][0][lw];
            char* nB = &lds[cur ^ 1][1][lw];
#pragma unroll
            for (int i = 0; i < 4; ++i) {
                *(intx4*)(nA + i * 1024) = pa[i];
                *(intx4*)(nB + i * 1024) = pb[i];
            }
        }
        __syncthreads();
    }

    size_t base = (size_t)s << 20;
#pragma unroll
    for (int mi = 0; mi < 4; ++mi) {
        int rowG = tm * 128 + wm * 64 + mi * 16 + q * 4;
#pragma unroll
        for (int ni = 0; ni < 4; ++ni) {
            int colG = tn * 128 + wn * 64 + ni * 16 + c;
#pragma unroll
            for (int r = 0; r < 4; ++r)
                P[base + (size_t)(rowG + r) * 1024 + colG] = acc[mi][ni][r];
        }
    }
}

// ---------------- reduce fp32 partials + bias + ReLU -> bf16 ----------------
__global__ __launch_bounds__(256) void reduce_k(const float* __restrict__ P,
                                                const float* __restrict__ bias,
                                                BF16* __restrict__ out,
                                                int S) {
    int i = blockIdx.x * 256 + threadIdx.x;
    float a = bias[i & 1023];
    for (int s = 0; s < S; ++s) a += P[((size_t)s << 20) + i];
    a = fmaxf(a, 0.0f);
    out[i] = __float2bfloat16(a);
}

// ---------------- heads: per-ROI block, fused fc2 reduce + softmax + decode ----
__global__ __launch_bounds__(256) void head_k(const float* __restrict__ P2,
                                              const float* __restrict__ fc2_b,
                                              const float* __restrict__ cls_w,
                                              const float* __restrict__ cls_b,
                                              const float* __restrict__ bbox_w,
                                              const float* __restrict__ bbox_b,
                                              const float* __restrict__ boxes,
                                              float* __restrict__ out, int S2) {
    __shared__ float red[4][10];
    int roi = blockIdx.x;
    int t = threadIdx.x, w = t >> 6, l = t & 63;
    int k4 = t * 4;

    floatx4 h = *(const floatx4*)(fc2_b + k4);
    const float* pbase = P2 + (size_t)roi * 1024 + k4;
    for (int s = 0; s < S2; ++s) {
        floatx4 p = *(const floatx4*)(pbase + ((size_t)s << 20));
        h.x += p.x; h.y += p.y; h.z += p.z; h.w += p.w;
    }
    h.x = fmaxf(h.x, 0.f); h.y = fmaxf(h.y, 0.f); h.z = fmaxf(h.z, 0.f); h.w = fmaxf(h.w, 0.f);

    float acc[10];
#pragma unroll
    for (int j = 0; j < 10; ++j) acc[j] = 0.0f;
    floatx4 c0 = *(const floatx4*)(cls_w + k4 * 2);
    floatx4 c1 = *(const floatx4*)(cls_w + k4 * 2 + 4);
    acc[0] = h.x * c0.x + h.y * c0.z + h.z * c1.x + h.w * c1.z;
    acc[1] = h.x * c0.y + h.y * c0.w + h.z * c1.y + h.w * c1.w;
    const float* bw = bbox_w + k4 * 8;
#pragma unroll
    for (int kk = 0; kk < 4; ++kk) {
        float hv = (kk == 0) ? h.x : (kk == 1) ? h.y : (kk == 2) ? h.z : h.w;
        floatx4 b0 = *(const floatx4*)(bw + kk * 8);
        floatx4 b1 = *(const floatx4*)(bw + kk * 8 + 4);
        acc[2] += hv * b0.x; acc[3] += hv * b0.y; acc[4] += hv * b0.z; acc[5] += hv * b0.w;
        acc[6] += hv * b1.x; acc[7] += hv * b1.y; acc[8] += hv * b1.z; acc[9] += hv * b1.w;
    }
#pragma unroll
    for (int j = 0; j < 10; ++j) {
#pragma unroll
        for (int off = 32; off > 0; off >>= 1) acc[j] += __shfl_down(acc[j], off);
    }
    if (l == 0) {
#pragma unroll
        for (int j = 0; j < 10; ++j) red[w][j] = acc[j];
    }
    __syncthreads();
    if (t == 0) {
        float f[10];
#pragma unroll
        for (int j = 0; j < 10; ++j) f[j] = red[0][j] + red[1][j] + red[2][j] + red[3][j];
        float s0 = f[0] + cls_b[0], s1 = f[1] + cls_b[1];
        float m = fmaxf(s0, s1);
        float e0 = expf(s0 - m), e1 = expf(s1 - m);
        float inv = 1.0f / (e0 + e1);

        float bx1 = boxes[roi * 4 + 0], by1 = boxes[roi * 4 + 1];
        float bx2 = boxes[roi * 4 + 2], by2 = boxes[roi * 4 + 3];
        float pw = bx2 - bx1, ph = by2 - by1;
        float cx = bx1 + 0.5f * pw, cy = by1 + 0.5f * ph;
        const float CLAMPV = 4.135166556742356f;
        float* orow = out + roi * 10;
#pragma unroll
        for (int cl = 0; cl < 2; ++cl) {
            float dx = (f[2 + cl * 4 + 0] + bbox_b[cl * 4 + 0]) * 0.1f;
            float dy = (f[2 + cl * 4 + 1] + bbox_b[cl * 4 + 1]) * 0.1f;
            float dw = fminf((f[2 + cl * 4 + 2] + bbox_b[cl * 4 + 2]) * 0.2f, CLAMPV);
            float dh = fminf((f[2 + cl * 4 + 3] + bbox_b[cl * 4 + 3]) * 0.2f, CLAMPV);
            float pcx = dx * pw + cx, pcy = dy * ph + cy;
            float pww = expf(dw) * pw, phh = expf(dh) * ph;
            orow[cl * 4 + 0] = fminf(fmaxf(pcx - 0.5f * pww, 0.0f), 1088.0f);
            orow[cl * 4 + 1] = fminf(fmaxf(pcy - 0.5f * phh, 0.0f), 800.0f);
            orow[cl * 4 + 2] = fminf(fmaxf(pcx + 0.5f * pww, 0.0f), 1088.0f);
            orow[cl * 4 + 3] = fminf(fmaxf(pcy + 0.5f * phh, 0.0f), 800.0f);
        }
        orow[8] = e0 * inv;
        orow[9] = e1 * inv;
    }
}

extern "C" void kernel_launch(void* const* d_in, const int* in_sizes, int n_in,
                              void* d_out, int out_size, void* d_ws, size_t ws_size,
                              hipStream_t stream) {
    const float* features = (const float*)d_in[0];
    const float* boxes    = (const float*)d_in[1];
    const int*   roi_b    = (const int*)d_in[2];
    const float* fc1_w    = (const float*)d_in[3];
    const float* fc1_b    = (const float*)d_in[4];
    const float* fc2_w    = (const float*)d_in[5];
    const float* fc2_b    = (const float*)d_in[6];
    const float* cls_w    = (const float*)d_in[7];
    const float* cls_b    = (const float*)d_in[8];
    const float* bbox_w   = (const float*)d_in[9];
    const float* bbox_b   = (const float*)d_in[10];
    float* out = (float*)d_out;

    char* ws = (char*)d_ws;
    BF16* featT = (BF16*)(ws + 0);           // [0, 13,926,400)
    BF16* w1t   = (BF16*)(ws + 13926400);    // [.., 39,616,512)
    BF16* w2t   = (BF16*)(ws + 39616512);    // [.., 41,713,664)
    BF16* feats = (BF16*)(ws + 41713664);    // [.., 67,403,776)
    BF16* h1    = (BF16*)(ws + 67403776);    // [.., 69,500,928)
    float* P1   = (float*)(ws + 69500928);   // 7 * 4 MB -> ends 98,861,056
    float* P2   = (float*)(ws + 0);          // 4 * 4 MB; reuses dead featT region

    int S1 = 7;   // 12544 = 7 * 1792, 1792 = 28 * 64
    int S2 = 4;   // 1024 = 4 * 256, 256 = 4 * 64

    transpose_all<<<20368, 256, 0, stream>>>(features, fc1_w, fc2_w, featT, w1t, w2t);

    roi_align_k<<<1024, 256, 0, stream>>>(featT, boxes, roi_b, feats);

    gemm_splitk<<<64 * S1, 256, 0, stream>>>(feats, w1t, P1, 12544, 12544 / S1);
    reduce_k<<<4096, 256, 0, stream>>>(P1, fc1_b, h1, S1);

    gemm_splitk<<<64 * S2, 256, 0, stream>>>(h1, w2t, P2, 1024, 1024 / S2);

    head_k<<<1000, 256, 0, stream>>>(P2, fc2_b, cls_w, cls_b, bbox_w, bbox_b, boxes, out, S2);
}